// Round 14
// baseline (404.994 us; speedup 1.0000x reference)
//
#include <hip/hip_runtime.h>
#include <hip/hip_bf16.h>
#include <stdint.h>

// ScaledDotProductAttention S=4096 D=1024 fp32.
// R20 = R16 (proven best: 45.6us dispatches, 206.9 wall, passed) + split-K
// fixup fused into G3 (removes reduce_out kernel + one ~13us launch gap).
// 8-phase line abandoned per pre-committed rule: 4 faithful attempts measured
// 53-73us vs 2-phase's 45.6 (R12/R13/R18/R19 post-mortems).
// Fixup protocol: all 4 z-blocks of an (m,n)-tile write partials exactly as
// R16 (z<3 bf16 normalized -> p_z, z=3 fp32 -> out); then release-fence
// (__threadfence: wbL2) + atomicAdd(cnt[tile]); the block drawing old==3
// acquire-fences (invL2 -- reader XCD L2 holds STALE Xb/Qb/Kb lines from
// G1/G2 reads; per-XCD L2s are not coherent) and sums the 3 bf16 partials
// onto out. Exactly-one reducer, no spinning (no deadlock), arithmetic
// identical to reduce_out => identical absmax. cnt (128 ints) zeroed by cvt.

typedef __bf16 bf16_t;
typedef __bf16 bf16x4 __attribute__((ext_vector_type(4)));
typedef __bf16 bf16x8 __attribute__((ext_vector_type(8)));
typedef float f32x4 __attribute__((ext_vector_type(4)));

#define AS1 __attribute__((address_space(1)))
#define AS3 __attribute__((address_space(3)))

__device__ __forceinline__ void async_ld16(const void* g, void* l) {
  // global -> LDS DMA, 16B/lane; LDS dest is wave-uniform base + lane*16 by HW rule.
  __builtin_amdgcn_global_load_lds((AS1 void*)g, (AS3 void*)l, 16, 0, 0);
}

// BM=256, BN=128, BK=64, 8 waves (4M x 2N), per-wave 64x64 output = acc[4][4].
// LDS: As 256x64 | Bs 128x64 bf16 = 48 KiB, single-buffered, 2 blocks/CU.
// MODE 0: QKV epilogue (bias; Q scaled 1/32; V transposed via LDS).
// MODE 1: S epilogue: store exp(acc) bf16 ldc=4096, atomicAdd fp32 row sums.
// MODE 2: O epilogue: zz<3 -> bf16 partial; zz==3 -> fp32 to fout; last of
//         the 4 z-blocks per tile reduces partials onto fout (fixup).
template <int MODE>
__global__ __launch_bounds__(512, 4) void gemm2(
    const bf16_t* __restrict__ A, const bf16_t* __restrict__ B, const int ld,
    const int Klen, bf16_t* __restrict__ o0, bf16_t* __restrict__ o1,
    bf16_t* __restrict__ o2, const float* __restrict__ b0,
    const float* __restrict__ b1, const float* __restrict__ b2,
    float* __restrict__ fout, float* __restrict__ rowsum) {
  __shared__ bf16_t smem[24576];  // As(16384) | Bs(8192) = 49152 B
  bf16_t* As = smem;
  bf16_t* Bs = smem + 16384;

  const int t = threadIdx.x;
  const int lane = t & 63;
  const int wave = t >> 6;
  const int wm = wave >> 1;   // 0..3  (M quarter, 64 rows)
  const int wn = wave & 1;    // 0..1  (N half, 64 cols)
  const int q = lane >> 4;
  const int l16 = lane & 15;
  const int xf = l16 & 7;

  // Grid decode: XCD-aware (bid&7 = XCD), bijective per mode (R16-proven).
  int m0, n0, k0 = 0, zz = 0;
  const int bid = blockIdx.x;
  if constexpr (MODE == 0) {
    // 384 blocks = 16m x 24n; per XCD: 4m x 12n region.
    const int x = bid & 7, sl = bid >> 3;  // sl 0..47
    m0 = ((x >> 1) * 4 + (sl & 3)) * 256;
    n0 = ((x & 1) * 12 + (sl >> 2)) * 128;
  } else if constexpr (MODE == 1) {
    // 512 blocks = 16m x 32n; per XCD: 8m x 8n region.
    const int x = bid & 7, sl = bid >> 3;  // sl 0..63
    m0 = ((x >> 2) * 8 + (sl >> 3)) * 256;
    n0 = ((x & 3) * 8 + (sl & 7)) * 128;
  } else {
    // 512 blocks: split-K z = x>>1; per XCD: 8m x 8n of one split (N=1024).
    const int x = bid & 7, sl = bid >> 3;  // sl 0..63
    zz = x >> 1;
    m0 = ((x & 1) * 8 + (sl >> 3)) * 256;
    n0 = (sl & 7) * 128;
    k0 = zz * Klen;
  }

  // Staging swizzle (R5-proven, conflict-free): GLOBAL chunk = slot ^ (srow&7);
  // LDS stays linear (HW rule). 64 rows x 64 k per DMA round (1 load/thread).
  const int srow = t >> 3;                      // 0..63
  const int c8s = ((t & 7) ^ (srow & 7)) * 8;
  const bf16_t* Ab = A + (size_t)(m0 + srow) * ld + k0 + c8s;
  const bf16_t* Bb = B + (size_t)(n0 + srow) * ld + k0 + c8s;
  const int tl8 = t * 8;

  const int ar = wm * 64 + l16;
  const int br = wn * 64 + l16;

  f32x4 acc[4][4];
  const f32x4 zero4 = {0.f, 0.f, 0.f, 0.f};
#pragma unroll
  for (int i = 0; i < 4; ++i)
#pragma unroll
    for (int j = 0; j < 4; ++j) acc[i][j] = zero4;

  for (int kt = 0; kt < Klen; kt += 64) {
    // Burst-stage tile: A 4 rounds (256 rows), B 2 rounds (128 rows).
#pragma unroll
    for (int rr = 0; rr < 4; ++rr)
      async_ld16(Ab + kt + (size_t)(rr * 64) * ld, As + rr * 4096 + tl8);
#pragma unroll
    for (int rr = 0; rr < 2; ++rr)
      async_ld16(Bb + kt + (size_t)(rr * 64) * ld, Bs + rr * 4096 + tl8);
    __syncthreads();  // vmcnt(0)+barrier: tile resident

#pragma unroll
    for (int s = 0; s < 2; ++s) {
      const int cs = ((s * 4 + q) ^ xf) * 8;
      bf16x8 fa[4], fb[4];
#pragma unroll
      for (int im = 0; im < 4; ++im)
        fa[im] = *(const bf16x8*)(As + (ar + im * 16) * 64 + cs);
#pragma unroll
      for (int j = 0; j < 4; ++j)
        fb[j] = *(const bf16x8*)(Bs + (br + j * 16) * 64 + cs);
#pragma unroll
      for (int im = 0; im < 4; ++im)
#pragma unroll
        for (int j = 0; j < 4; ++j)
          acc[im][j] = __builtin_amdgcn_mfma_f32_16x16x32_bf16(
              fa[im], fb[j], acc[im][j], 0, 0, 0);
    }
    __syncthreads();  // compute done; next stage may overwrite
  }

  // C/D layout: col = lane&15, row = quad*4 + reg (m89/m91-verified).
  const int mBase = m0 + wm * 64 + q * 4;  // + im*16 + r

  if constexpr (MODE == 0) {
    const int sel = n0 >> 10;  // 0=Q 1=K 2=V  (128-tiles never straddle)
    const int nl0 = (n0 & 1023) + wn * 64 + l16;
    if (sel < 2) {
      const float* bias = (sel == 0) ? b0 : b1;
      const float sc = (sel == 0) ? 0.03125f : 1.0f;  // 1/sqrt(1024) in Q
      bf16_t* dst = (sel == 0) ? o0 : o1;
      float bb[4];
#pragma unroll
      for (int j = 0; j < 4; ++j) bb[j] = bias[nl0 + j * 16];
      // j INNERMOST: 4 consecutive stores complete each 128B run (R13 fix).
#pragma unroll
      for (int im = 0; im < 4; ++im) {
        const int mr = mBase + im * 16;
#pragma unroll
        for (int r = 0; r < 4; ++r)
#pragma unroll
          for (int j = 0; j < 4; ++j)
            dst[(size_t)(mr + r) * 1024 + nl0 + j * 16] =
                (bf16_t)((acc[im][j][r] + bb[j]) * sc);
      }
    } else {
      // V^T via LDS transpose: two passes of 64 d-rows x 256 m. Stride 264
      // elems: write banks 4*l16 (2 lanes/bank = free, m136); drain 16B/lane,
      // 512B-contiguous per Vt row -> full-line stores.
      bf16_t* vs = smem;  // 64*264*2 = 33792 B <= 49152 (K-loop buffers dead)
      const int dg0 = n0 & 1023;
#pragma unroll
      for (int h = 0; h < 2; ++h) {
        if (wn == h) {
#pragma unroll
          for (int j = 0; j < 4; ++j) {
            const int dl = j * 16 + l16;  // 0..63 within this half
            const float bb = b2[dg0 + h * 64 + dl];
#pragma unroll
            for (int im = 0; im < 4; ++im) {
              bf16x4 v;
#pragma unroll
              for (int r = 0; r < 4; ++r) v[r] = (bf16_t)(acc[im][j][r] + bb);
              *(bf16x4*)(vs + dl * 264 + wm * 64 + im * 16 + q * 4) = v;
            }
          }
        }
        __syncthreads();
#pragma unroll
        for (int rr = 0; rr < 4; ++rr) {
          const int task = rr * 512 + t;  // 2048 tasks = 64 rows x 32 chunks
          const int row = task >> 5, ck = task & 31;
          *(bf16x8*)(o2 + (size_t)(dg0 + h * 64 + row) * 4096 + m0 + ck * 8) =
              *(const bf16x8*)(vs + row * 264 + ck * 8);
        }
        __syncthreads();
      }
    }
  } else if constexpr (MODE == 1) {
    float ps[4][4];
#pragma unroll
    for (int im = 0; im < 4; ++im)
#pragma unroll
      for (int r = 0; r < 4; ++r) ps[im][r] = 0.f;
    const int nb = n0 + wn * 64 + l16;
    // j INNERMOST: complete 128B runs back-to-back (R13 write-combine fix).
#pragma unroll
    for (int im = 0; im < 4; ++im) {
      const int mr = mBase + im * 16;
#pragma unroll
      for (int r = 0; r < 4; ++r)
#pragma unroll
        for (int j = 0; j < 4; ++j) {
          const float e = __expf(acc[im][j][r]);
          ps[im][r] += e;
          o0[(size_t)(mr + r) * 4096 + nb + j * 16] = (bf16_t)e;
        }
    }
#pragma unroll
    for (int im = 0; im < 4; ++im)
#pragma unroll
      for (int r = 0; r < 4; ++r) {
        float v = ps[im][r];
        v += __shfl_xor(v, 1);
        v += __shfl_xor(v, 2);
        v += __shfl_xor(v, 4);
        v += __shfl_xor(v, 8);
        ps[im][r] = v;
      }
    if (l16 == 0) {
#pragma unroll
      for (int im = 0; im < 4; ++im)
#pragma unroll
        for (int r = 0; r < 4; ++r)
          atomicAdd(rowsum + mBase + im * 16 + r, ps[im][r]);
    }
  } else {
    float inv[4][4];
#pragma unroll
    for (int im = 0; im < 4; ++im)
#pragma unroll
      for (int r = 0; r < 4; ++r)
        inv[im][r] = 1.0f / rowsum[mBase + im * 16 + r];
    const int nb = n0 + wn * 64 + l16;
    if (zz < 3) {  // bf16 partial (normalized); partials over splits sum to O
      bf16_t* pp = (zz == 0) ? o0 : ((zz == 1) ? o1 : o2);
#pragma unroll
      for (int im = 0; im < 4; ++im) {
        const int mr = mBase + im * 16;
#pragma unroll
        for (int r = 0; r < 4; ++r) {
          const float iv = inv[im][r];
#pragma unroll
          for (int j = 0; j < 4; ++j)
            pp[(size_t)(mr + r) * 1024 + nb + j * 16] =
                (bf16_t)(acc[im][j][r] * iv);
        }
      }
    } else {  // zz==3: fp32 base straight into d_out; fixup adds the rest
#pragma unroll
      for (int im = 0; im < 4; ++im) {
        const int mr = mBase + im * 16;
#pragma unroll
        for (int r = 0; r < 4; ++r) {
          const float iv = inv[im][r];
#pragma unroll
          for (int j = 0; j < 4; ++j)
            fout[(size_t)(mr + r) * 1024 + nb + j * 16] = acc[im][j][r] * iv;
        }
      }
    }
    // ---- split-K fixup (R20): last of the 4 z-blocks reduces this tile.
    __threadfence();  // release: wbL2 -> our partial visible at L3
    __shared__ int lastArrive;
    if (t == 0) {
      int* cnt = (int*)(rowsum + 4096);           // 128 counters after rowsum
      const int tile = ((m0 >> 8) << 3) | (n0 >> 7);
      lastArrive = (atomicAdd(cnt + tile, 1) == 3);
    }
    __syncthreads();
    if (lastArrive) {
      __threadfence();  // acquire: invL2 -> fresh reads of partials + out
                        // (reader XCD L2 holds stale Xb/Qb/Kb lines from G1/G2)
#pragma unroll
      for (int rr = 0; rr < 8; ++rr) {
        const int task = rr * 512 + t;  // 4096 tasks = 256 rows x 16 chunks
        const int row = task >> 4, ck = task & 15;
        const size_t off = (size_t)(m0 + row) * 1024 + n0 + ck * 8;
        const bf16x8 a = *(const bf16x8*)(o0 + off);
        const bf16x8 b = *(const bf16x8*)(o1 + off);
        const bf16x8 c = *(const bf16x8*)(o2 + off);
        float4 lo = *(float4*)(fout + off);
        float4 hi = *(float4*)(fout + off + 4);
        lo.x += (float)a[0] + (float)b[0] + (float)c[0];
        lo.y += (float)a[1] + (float)b[1] + (float)c[1];
        lo.z += (float)a[2] + (float)b[2] + (float)c[2];
        lo.w += (float)a[3] + (float)b[3] + (float)c[3];
        hi.x += (float)a[4] + (float)b[4] + (float)c[4];
        hi.y += (float)a[5] + (float)b[5] + (float)c[5];
        hi.z += (float)a[6] + (float)b[6] + (float)c[6];
        hi.w += (float)a[7] + (float)b[7] + (float)c[7];
        *(float4*)(fout + off) = lo;
        *(float4*)(fout + off + 4) = hi;
      }
    }
  }
}

// Converts X|Wq|Wk|Wv to bf16; tail blocks zero rowsum (4096 f32) + the 128
// split-K fixup counters that follow it.
__global__ __launch_bounds__(256) void cvt_all(
    const float* __restrict__ X, const float* __restrict__ Wq,
    const float* __restrict__ Wk, const float* __restrict__ Wv,
    bf16_t* __restrict__ Xb, bf16_t* __restrict__ Wb,
    float* __restrict__ rowsum) {
  int i = blockIdx.x * 256 + threadIdx.x;
  if (i >= 1835008) {
    const int k = i - 1835008;
    if (k < 4224) rowsum[k] = 0.f;  // rowsum[4096] + cnt[128] (0.f == 0 bits)
    return;
  }
  const float* src;
  bf16_t* dst;
  int off;
  if (i < 1048576) {
    src = X; dst = Xb; off = i;
  } else {
    const int w = i - 1048576;
    const int sel = w >> 18;
    off = w & 0x3FFFF;
    src = (sel == 0) ? Wq : ((sel == 1) ? Wk : Wv);
    dst = Wb + (size_t)sel * (1024 * 1024);
  }
  const float4 v = ((const float4*)src)[off];
  bf16x4 o;
  o[0] = (bf16_t)v.x; o[1] = (bf16_t)v.y; o[2] = (bf16_t)v.z; o[3] = (bf16_t)v.w;
  ((bf16x4*)dst)[off] = o;
}

extern "C" void kernel_launch(void* const* d_in, const int* in_sizes, int n_in,
                              void* d_out, int out_size, void* d_ws,
                              size_t ws_size, hipStream_t stream) {
  const int S = 4096, D = 1024;
  const float* X  = (const float*)d_in[0];
  const float* Wq = (const float*)d_in[1];
  const float* bq = (const float*)d_in[2];
  const float* Wk = (const float*)d_in[3];
  const float* bk = (const float*)d_in[4];
  const float* Wv = (const float*)d_in[5];
  const float* bv = (const float*)d_in[6];
  float* out = (float*)d_out;

  // ws layout (70 MB bf16 + 16.5 KB fp32). G3 split-K=4 partials reuse dead
  // regions: Xb (dead after G1), Qb, Kb (dead after G2); z=3 goes to d_out.
  bf16_t* Xb = (bf16_t*)d_ws;            // [4096][1024]
  bf16_t* Wb = Xb + (size_t)S * D;       // [3072][1024]
  bf16_t* Qb = Wb + (size_t)3 * D * D;   // [4096][1024], pre-scaled by 1/32
  bf16_t* Kb = Qb + (size_t)S * D;       // [4096][1024]
  bf16_t* Vt = Kb + (size_t)S * D;       // [1024][4096]  V transposed
  bf16_t* Sc = Vt + (size_t)D * S;       // [4096][4096]  exp(scores)
  float* rowsum = (float*)(Sc + (size_t)S * S);  // [4096] + cnt[128]

  cvt_all<<<7185, 256, 0, stream>>>(X, Wq, Wk, Wv, Xb, Wb, rowsum);

  // G1: QKV = Xb @ Wb^T + bias  (M=4096, N=3072, K=1024), 384 blocks
  gemm2<0><<<384, 512, 0, stream>>>(
      Xb, Wb, D, D, Qb, Kb, Vt, bq, bk, bv, nullptr, nullptr);
  // G2: Sc = exp(Qb @ Kb^T), rowsum partials  (M=N=4096, K=1024), 512 blocks
  gemm2<1><<<512, 512, 0, stream>>>(
      Qb, Kb, D, D, Sc, nullptr, nullptr, nullptr, nullptr, nullptr, nullptr,
      rowsum);
  // G3: O = (Sc @ Vt^T)/rowsum, K split 4x1024, 512 blocks, fused fixup
  gemm2<2><<<512, 512, 0, stream>>>(
      Sc, Vt, S, S / 4, Xb, Qb, Kb, nullptr, nullptr, nullptr, out, rowsum);
}

// Round 15
// 202.620 us; speedup vs baseline: 1.9988x; 1.9988x over previous
//
#include <hip/hip_runtime.h>
#include <hip/hip_bf16.h>
#include <stdint.h>

// ScaledDotProductAttention S=4096 D=1024 fp32.
// R21 = R16 verbatim (proven best: 45.6us dispatches, 206.9us wall, passed).
// R20's fused split-K fixup REVERTED: per-block __threadfence() = full L2
// wb+inv per block -> 512 serialized L2 flushes -> G3 45.6->280us (measured).
// A kernel boundary does that flush ONCE device-wide; the separate reduce_out
// kernel is structurally cheaper than in-kernel cross-XCD reduction.
// Config (measured law R14/R15/R16): global_load_lds streams ~8 B/cy per
// concurrently-streaming block -> max tile intensity SUBJECT TO 2 blocks/CU.
// BM=256 BN=128 BK=64, 8 waves (4Mx2N), per-wave 64x64 acc, 48KB LDS x2
// blocks/CU. j-innermost epilogue stores (R13-measured WC fix: WRITE ideal).

typedef __bf16 bf16_t;
typedef __bf16 bf16x4 __attribute__((ext_vector_type(4)));
typedef __bf16 bf16x8 __attribute__((ext_vector_type(8)));
typedef float f32x4 __attribute__((ext_vector_type(4)));

#define AS1 __attribute__((address_space(1)))
#define AS3 __attribute__((address_space(3)))

__device__ __forceinline__ void async_ld16(const void* g, void* l) {
  // global -> LDS DMA, 16B/lane; LDS dest is wave-uniform base + lane*16 by HW rule.
  __builtin_amdgcn_global_load_lds((AS1 void*)g, (AS3 void*)l, 16, 0, 0);
}

// BM=256, BN=128, BK=64, 8 waves (4M x 2N), per-wave 64x64 output = acc[4][4].
// LDS: As 256x64 | Bs 128x64 bf16 = 48 KiB, single-buffered, 2 blocks/CU.
// MODE 0: QKV epilogue (bias; Q scaled 1/32; V transposed via LDS).
// MODE 1: S epilogue: store exp(acc) bf16 ldc=4096, atomicAdd fp32 row sums.
// MODE 2: O epilogue: zz<3 -> bf16 partial; zz==3 -> fp32 to fout (1/rowsum).
template <int MODE>
__global__ __launch_bounds__(512, 4) void gemm2(
    const bf16_t* __restrict__ A, const bf16_t* __restrict__ B, const int ld,
    const int Klen, bf16_t* __restrict__ o0, bf16_t* __restrict__ o1,
    bf16_t* __restrict__ o2, const float* __restrict__ b0,
    const float* __restrict__ b1, const float* __restrict__ b2,
    float* __restrict__ fout, float* __restrict__ rowsum) {
  __shared__ bf16_t smem[24576];  // As(16384) | Bs(8192) = 49152 B
  bf16_t* As = smem;
  bf16_t* Bs = smem + 16384;

  const int t = threadIdx.x;
  const int lane = t & 63;
  const int wave = t >> 6;
  const int wm = wave >> 1;   // 0..3  (M quarter, 64 rows)
  const int wn = wave & 1;    // 0..1  (N half, 64 cols)
  const int q = lane >> 4;
  const int l16 = lane & 15;
  const int xf = l16 & 7;

  // Grid decode: XCD-aware (bid&7 = XCD), bijective per mode (R16-proven).
  int m0, n0, k0 = 0, zz = 0;
  const int bid = blockIdx.x;
  if constexpr (MODE == 0) {
    // 384 blocks = 16m x 24n; per XCD: 4m x 12n region.
    const int x = bid & 7, sl = bid >> 3;  // sl 0..47
    m0 = ((x >> 1) * 4 + (sl & 3)) * 256;
    n0 = ((x & 1) * 12 + (sl >> 2)) * 128;
  } else if constexpr (MODE == 1) {
    // 512 blocks = 16m x 32n; per XCD: 8m x 8n region.
    const int x = bid & 7, sl = bid >> 3;  // sl 0..63
    m0 = ((x >> 2) * 8 + (sl >> 3)) * 256;
    n0 = ((x & 3) * 8 + (sl & 7)) * 128;
  } else {
    // 512 blocks: split-K z = x>>1; per XCD: 8m x 8n of one split (N=1024).
    const int x = bid & 7, sl = bid >> 3;  // sl 0..63
    zz = x >> 1;
    m0 = ((x & 1) * 8 + (sl >> 3)) * 256;
    n0 = (sl & 7) * 128;
    k0 = zz * Klen;
  }

  // Staging swizzle (R5-proven, conflict-free): GLOBAL chunk = slot ^ (srow&7);
  // LDS stays linear (HW rule). 64 rows x 64 k per DMA round (1 load/thread).
  const int srow = t >> 3;                      // 0..63
  const int c8s = ((t & 7) ^ (srow & 7)) * 8;
  const bf16_t* Ab = A + (size_t)(m0 + srow) * ld + k0 + c8s;
  const bf16_t* Bb = B + (size_t)(n0 + srow) * ld + k0 + c8s;
  const int tl8 = t * 8;

  const int ar = wm * 64 + l16;
  const int br = wn * 64 + l16;

  f32x4 acc[4][4];
  const f32x4 zero4 = {0.f, 0.f, 0.f, 0.f};
#pragma unroll
  for (int i = 0; i < 4; ++i)
#pragma unroll
    for (int j = 0; j < 4; ++j) acc[i][j] = zero4;

  for (int kt = 0; kt < Klen; kt += 64) {
    // Burst-stage tile: A 4 rounds (256 rows), B 2 rounds (128 rows).
#pragma unroll
    for (int rr = 0; rr < 4; ++rr)
      async_ld16(Ab + kt + (size_t)(rr * 64) * ld, As + rr * 4096 + tl8);
#pragma unroll
    for (int rr = 0; rr < 2; ++rr)
      async_ld16(Bb + kt + (size_t)(rr * 64) * ld, Bs + rr * 4096 + tl8);
    __syncthreads();  // vmcnt(0)+barrier: tile resident

#pragma unroll
    for (int s = 0; s < 2; ++s) {
      const int cs = ((s * 4 + q) ^ xf) * 8;
      bf16x8 fa[4], fb[4];
#pragma unroll
      for (int im = 0; im < 4; ++im)
        fa[im] = *(const bf16x8*)(As + (ar + im * 16) * 64 + cs);
#pragma unroll
      for (int j = 0; j < 4; ++j)
        fb[j] = *(const bf16x8*)(Bs + (br + j * 16) * 64 + cs);
#pragma unroll
      for (int im = 0; im < 4; ++im)
#pragma unroll
        for (int j = 0; j < 4; ++j)
          acc[im][j] = __builtin_amdgcn_mfma_f32_16x16x32_bf16(
              fa[im], fb[j], acc[im][j], 0, 0, 0);
    }
    __syncthreads();  // compute done; next stage may overwrite
  }

  // C/D layout: col = lane&15, row = quad*4 + reg (m89/m91-verified).
  const int mBase = m0 + wm * 64 + q * 4;  // + im*16 + r

  if constexpr (MODE == 0) {
    const int sel = n0 >> 10;  // 0=Q 1=K 2=V  (128-tiles never straddle)
    const int nl0 = (n0 & 1023) + wn * 64 + l16;
    if (sel < 2) {
      const float* bias = (sel == 0) ? b0 : b1;
      const float sc = (sel == 0) ? 0.03125f : 1.0f;  // 1/sqrt(1024) in Q
      bf16_t* dst = (sel == 0) ? o0 : o1;
      float bb[4];
#pragma unroll
      for (int j = 0; j < 4; ++j) bb[j] = bias[nl0 + j * 16];
      // j INNERMOST: 4 consecutive stores complete each 128B run (R13 fix).
#pragma unroll
      for (int im = 0; im < 4; ++im) {
        const int mr = mBase + im * 16;
#pragma unroll
        for (int r = 0; r < 4; ++r)
#pragma unroll
          for (int j = 0; j < 4; ++j)
            dst[(size_t)(mr + r) * 1024 + nl0 + j * 16] =
                (bf16_t)((acc[im][j][r] + bb[j]) * sc);
      }
    } else {
      // V^T via LDS transpose: two passes of 64 d-rows x 256 m. Stride 264
      // elems: write banks 4*l16 (2 lanes/bank = free, m136); drain 16B/lane,
      // 512B-contiguous per Vt row -> full-line stores.
      bf16_t* vs = smem;  // 64*264*2 = 33792 B <= 49152 (K-loop buffers dead)
      const int dg0 = n0 & 1023;
#pragma unroll
      for (int h = 0; h < 2; ++h) {
        if (wn == h) {
#pragma unroll
          for (int j = 0; j < 4; ++j) {
            const int dl = j * 16 + l16;  // 0..63 within this half
            const float bb = b2[dg0 + h * 64 + dl];
#pragma unroll
            for (int im = 0; im < 4; ++im) {
              bf16x4 v;
#pragma unroll
              for (int r = 0; r < 4; ++r) v[r] = (bf16_t)(acc[im][j][r] + bb);
              *(bf16x4*)(vs + dl * 264 + wm * 64 + im * 16 + q * 4) = v;
            }
          }
        }
        __syncthreads();
#pragma unroll
        for (int rr = 0; rr < 4; ++rr) {
          const int task = rr * 512 + t;  // 2048 tasks = 64 rows x 32 chunks
          const int row = task >> 5, ck = task & 31;
          *(bf16x8*)(o2 + (size_t)(dg0 + h * 64 + row) * 4096 + m0 + ck * 8) =
              *(const bf16x8*)(vs + row * 264 + ck * 8);
        }
        __syncthreads();
      }
    }
  } else if constexpr (MODE == 1) {
    float ps[4][4];
#pragma unroll
    for (int im = 0; im < 4; ++im)
#pragma unroll
      for (int r = 0; r < 4; ++r) ps[im][r] = 0.f;
    const int nb = n0 + wn * 64 + l16;
    // j INNERMOST: complete 128B runs back-to-back (R13 write-combine fix).
#pragma unroll
    for (int im = 0; im < 4; ++im) {
      const int mr = mBase + im * 16;
#pragma unroll
      for (int r = 0; r < 4; ++r)
#pragma unroll
        for (int j = 0; j < 4; ++j) {
          const float e = __expf(acc[im][j][r]);
          ps[im][r] += e;
          o0[(size_t)(mr + r) * 4096 + nb + j * 16] = (bf16_t)e;
        }
    }
#pragma unroll
    for (int im = 0; im < 4; ++im)
#pragma unroll
      for (int r = 0; r < 4; ++r) {
        float v = ps[im][r];
        v += __shfl_xor(v, 1);
        v += __shfl_xor(v, 2);
        v += __shfl_xor(v, 4);
        v += __shfl_xor(v, 8);
        ps[im][r] = v;
      }
    if (l16 == 0) {
#pragma unroll
      for (int im = 0; im < 4; ++im)
#pragma unroll
        for (int r = 0; r < 4; ++r)
          atomicAdd(rowsum + mBase + im * 16 + r, ps[im][r]);
    }
  } else {
    float inv[4][4];
#pragma unroll
    for (int im = 0; im < 4; ++im)
#pragma unroll
      for (int r = 0; r < 4; ++r)
        inv[im][r] = 1.0f / rowsum[mBase + im * 16 + r];
    const int nb = n0 + wn * 64 + l16;
    if (zz < 3) {  // bf16 partial (normalized); partials over splits sum to O
      bf16_t* pp = (zz == 0) ? o0 : ((zz == 1) ? o1 : o2);
#pragma unroll
      for (int im = 0; im < 4; ++im) {
        const int mr = mBase + im * 16;
#pragma unroll
        for (int r = 0; r < 4; ++r) {
          const float iv = inv[im][r];
#pragma unroll
          for (int j = 0; j < 4; ++j)
            pp[(size_t)(mr + r) * 1024 + nb + j * 16] =
                (bf16_t)(acc[im][j][r] * iv);
        }
      }
    } else {  // zz==3: fp32 partial straight into d_out; reduce adds the rest
#pragma unroll
      for (int im = 0; im < 4; ++im) {
        const int mr = mBase + im * 16;
#pragma unroll
        for (int r = 0; r < 4; ++r) {
          const float iv = inv[im][r];
#pragma unroll
          for (int j = 0; j < 4; ++j)
            fout[(size_t)(mr + r) * 1024 + nb + j * 16] = acc[im][j][r] * iv;
        }
      }
    }
  }
}

// Converts X|Wq|Wk|Wv to bf16; last 16 blocks zero rowsum (4096 f32).
__global__ __launch_bounds__(256) void cvt_all(
    const float* __restrict__ X, const float* __restrict__ Wq,
    const float* __restrict__ Wk, const float* __restrict__ Wv,
    bf16_t* __restrict__ Xb, bf16_t* __restrict__ Wb,
    float* __restrict__ rowsum) {
  int i = blockIdx.x * 256 + threadIdx.x;
  if (i >= 1835008) {
    rowsum[i - 1835008] = 0.f;
    return;
  }
  const float* src;
  bf16_t* dst;
  int off;
  if (i < 1048576) {
    src = X; dst = Xb; off = i;
  } else {
    const int w = i - 1048576;
    const int sel = w >> 18;
    off = w & 0x3FFFF;
    src = (sel == 0) ? Wq : ((sel == 1) ? Wk : Wv);
    dst = Wb + (size_t)sel * (1024 * 1024);
  }
  const float4 v = ((const float4*)src)[off];
  bf16x4 o;
  o[0] = (bf16_t)v.x; o[1] = (bf16_t)v.y; o[2] = (bf16_t)v.z; o[3] = (bf16_t)v.w;
  ((bf16x4*)dst)[off] = o;
}

// out[i] += f32(p0[i]) + f32(p1[i]) + f32(p2[i]);  8 elems/thread.
__global__ __launch_bounds__(256) void reduce_out(
    const bf16_t* __restrict__ p0, const bf16_t* __restrict__ p1,
    const bf16_t* __restrict__ p2, float* __restrict__ out) {
  const int i = blockIdx.x * 256 + threadIdx.x;
  const bf16x8 a = ((const bf16x8*)p0)[i];
  const bf16x8 b = ((const bf16x8*)p1)[i];
  const bf16x8 c = ((const bf16x8*)p2)[i];
  float4 lo = ((const float4*)out)[2 * i];
  float4 hi = ((const float4*)out)[2 * i + 1];
  lo.x += (float)a[0] + (float)b[0] + (float)c[0];
  lo.y += (float)a[1] + (float)b[1] + (float)c[1];
  lo.z += (float)a[2] + (float)b[2] + (float)c[2];
  lo.w += (float)a[3] + (float)b[3] + (float)c[3];
  hi.x += (float)a[4] + (float)b[4] + (float)c[4];
  hi.y += (float)a[5] + (float)b[5] + (float)c[5];
  hi.z += (float)a[6] + (float)b[6] + (float)c[6];
  hi.w += (float)a[7] + (float)b[7] + (float)c[7];
  ((float4*)out)[2 * i] = lo;
  ((float4*)out)[2 * i + 1] = hi;
}

extern "C" void kernel_launch(void* const* d_in, const int* in_sizes, int n_in,
                              void* d_out, int out_size, void* d_ws,
                              size_t ws_size, hipStream_t stream) {
  const int S = 4096, D = 1024;
  const float* X  = (const float*)d_in[0];
  const float* Wq = (const float*)d_in[1];
  const float* bq = (const float*)d_in[2];
  const float* Wk = (const float*)d_in[3];
  const float* bk = (const float*)d_in[4];
  const float* Wv = (const float*)d_in[5];
  const float* bv = (const float*)d_in[6];
  float* out = (float*)d_out;

  // ws layout (70 MB bf16 + 16 KB fp32). G3 split-K=4 partials reuse dead
  // regions: Xb (dead after G1), Qb, Kb (dead after G2); z=3 goes to d_out.
  bf16_t* Xb = (bf16_t*)d_ws;            // [4096][1024]
  bf16_t* Wb = Xb + (size_t)S * D;       // [3072][1024]
  bf16_t* Qb = Wb + (size_t)3 * D * D;   // [4096][1024], pre-scaled by 1/32
  bf16_t* Kb = Qb + (size_t)S * D;       // [4096][1024]
  bf16_t* Vt = Kb + (size_t)S * D;       // [1024][4096]  V transposed
  bf16_t* Sc = Vt + (size_t)D * S;       // [4096][4096]  exp(scores)
  float* rowsum = (float*)(Sc + (size_t)S * S);  // [4096]

  cvt_all<<<7184, 256, 0, stream>>>(X, Wq, Wk, Wv, Xb, Wb, rowsum);

  // G1: QKV = Xb @ Wb^T + bias  (M=4096, N=3072, K=1024), 384 blocks
  gemm2<0><<<384, 512, 0, stream>>>(
      Xb, Wb, D, D, Qb, Kb, Vt, bq, bk, bv, nullptr, nullptr);
  // G2: Sc = exp(Qb @ Kb^T), rowsum partials  (M=N=4096, K=1024), 512 blocks
  gemm2<1><<<512, 512, 0, stream>>>(
      Qb, Kb, D, D, Sc, nullptr, nullptr, nullptr, nullptr, nullptr, nullptr,
      rowsum);
  // G3: O-partials = (Sc @ Vt^T)/rowsum, K split 4x1024, 512 blocks
  gemm2<2><<<512, 512, 0, stream>>>(
      Sc, Vt, S, S / 4, Xb, Qb, Kb, nullptr, nullptr, nullptr, out, rowsum);
  // out += p0 + p1 + p2
  reduce_out<<<S * D / 8 / 256, 256, 0, stream>>>(Xb, Qb, Kb, out);
}